// Round 4
// baseline (894.985 us; speedup 1.0000x reference)
//
#include <hip/hip_runtime.h>
#include <hip/hip_bf16.h>
#include <cstdint>
#include <cstddef>

#define BB 64
#define NN 512
#define MM 512
#define DD 128

static constexpr float SINK_EPS_F = 0.05f;
static constexpr int   ITERS      = 80;
static constexpr float A_CONST    = 1.0f / 512.0f;
static constexpr float B_CONST    = 1.0f / 512.0f;

typedef __attribute__((ext_vector_type(8))) short bf16x8;
typedef __attribute__((ext_vector_type(4))) float f32x4;

__device__ __forceinline__ float bflo(unsigned u) { return __uint_as_float(u << 16); }
__device__ __forceinline__ float bfhi(unsigned u) { return __uint_as_float(u & 0xffff0000u); }

__device__ __forceinline__ float fdot2bf(unsigned a, unsigned b, float c) {
    asm("v_dot2_f32_bf16 %0, %1, %2, %0" : "+v"(c) : "v"(a), "v"(b));
    return c;
}
__device__ __forceinline__ unsigned short bfr(float x) {
    __hip_bfloat16 h = __float2bfloat16(x);
    return *reinterpret_cast<unsigned short*>(&h);
}
__device__ __forceinline__ unsigned pack2(float lo, float hi) {
    return (unsigned)bfr(lo) | ((unsigned)bfr(hi) << 16);
}
__device__ __forceinline__ uint2 pk4(float4 v) {
    uint2 r;
    r.x = (unsigned)bfr(v.x) | ((unsigned)bfr(v.y) << 16);
    r.y = (unsigned)bfr(v.z) | ((unsigned)bfr(v.w) << 16);
    return r;
}

// ---------------- kernel 1: row inverse norms ----------------
__global__ __launch_bounds__(256) void norm_kernel(const float* __restrict__ src,
                                                   const float* __restrict__ tgt,
                                                   float* __restrict__ inv_ns,
                                                   float* __restrict__ inv_nt) {
    int wave = (blockIdx.x * blockDim.x + threadIdx.x) >> 6;
    int lane = threadIdx.x & 63;
    const float* row;
    float* out;
    if (wave < BB * NN) { row = src + (size_t)wave * DD; out = inv_ns + wave; }
    else                { row = tgt + (size_t)(wave - BB * NN) * DD; out = inv_nt + (wave - BB * NN); }
    float2 v = ((const float2*)row)[lane];
    float s = v.x * v.x + v.y * v.y;
    #pragma unroll
    for (int off = 32; off; off >>= 1) s += __shfl_xor(s, off, 64);
    if (lane == 0) *out = 1.0f / fmaxf(sqrtf(s), 1e-12f);
}

// ---------------- kernel 2: MFMA bf16 cost GEMM -> W = exp(-C/eps) ----------------
#define RS 136   // ushort row stride: 272B -> frag ds_read row-bank step 4, 2-way (free)

__global__ __launch_bounds__(256) void cost_mfma_kernel(const float* __restrict__ S,
                                                        const float* __restrict__ T,
                                                        const float* __restrict__ inv_ns,
                                                        const float* __restrict__ inv_nt,
                                                        unsigned short* __restrict__ W) {
    __shared__ unsigned short sA[128 * RS];
    __shared__ unsigned short sB[128 * RS];
    int bid = blockIdx.x;
    int b  = bid >> 4;
    int i0 = ((bid >> 2) & 3) * 128;
    int j0 = (bid & 3) * 128;
    int t  = threadIdx.x;

    // stage normalized bf16 tiles (full K=128, single stage)
    {
        int r = t >> 1, h = t & 1;
        int gra = b * NN + i0 + r;
        int grb = b * MM + j0 + r;
        float sca = inv_ns[gra], scb = inv_nt[grb];
        const float4* pS = (const float4*)(S + (size_t)gra * DD + h * 64);
        const float4* pT = (const float4*)(T + (size_t)grb * DD + h * 64);
        unsigned short* dA = &sA[r * RS + h * 64];
        unsigned short* dB = &sB[r * RS + h * 64];
        #pragma unroll
        for (int c4 = 0; c4 < 16; ++c4) {
            float4 v = pS[c4];
            v.x *= sca; v.y *= sca; v.z *= sca; v.w *= sca;
            *(uint2*)&dA[c4 * 4] = pk4(v);
            float4 u = pT[c4];
            u.x *= scb; u.y *= scb; u.z *= scb; u.w *= scb;
            *(uint2*)&dB[c4 * 4] = pk4(u);
        }
    }
    __syncthreads();

    int l = t & 63, w = t >> 6;
    int wr = (w >> 1) * 64, wc = (w & 1) * 64;
    int fr = l & 15, fo = (l >> 4) * 8;

    f32x4 acc[4][4];
    #pragma unroll
    for (int m = 0; m < 4; ++m)
        #pragma unroll
        for (int n = 0; n < 4; ++n)
            acc[m][n] = (f32x4){0.f, 0.f, 0.f, 0.f};

    #pragma unroll
    for (int kk = 0; kk < 4; ++kk) {
        bf16x8 af[4], bfv[4];
        #pragma unroll
        for (int m = 0; m < 4; ++m)
            af[m] = *(bf16x8*)&sA[(wr + m * 16 + fr) * RS + kk * 32 + fo];
        #pragma unroll
        for (int n = 0; n < 4; ++n)
            bfv[n] = *(bf16x8*)&sB[(wc + n * 16 + fr) * RS + kk * 32 + fo];
        #pragma unroll
        for (int m = 0; m < 4; ++m)
            #pragma unroll
            for (int n = 0; n < 4; ++n)
                acc[m][n] = __builtin_amdgcn_mfma_f32_16x16x32_bf16(af[m], bfv[n], acc[m][n], 0, 0, 0);
    }

    // epilogue: C/D layout col=lane&15, row=(lane>>4)*4+reg
    int rb = (l >> 4) * 4;
    #pragma unroll
    for (int m = 0; m < 4; ++m) {
        #pragma unroll
        for (int n = 0; n < 4; ++n) {
            #pragma unroll
            for (int r = 0; r < 4; ++r) {
                int gi = b * NN + i0 + wr + m * 16 + rb + r;
                int gj = j0 + wc + n * 16 + fr;
                float c = acc[m][n][r];
                float cost = fmaxf(2.0f - 2.0f * c, 0.0f);
                W[(size_t)gi * MM + gj] = bfr(__expf(-20.0f * cost));
            }
        }
    }
}

// ---------------- kernel 3: column-slab Sinkhorn, lean syncs + prefetch ----------------
// Block (b,q) owns W[b][:, 128q..128q+128). Partials in Sp[buf][b][row][q] so the
// gather is contiguous 32B per thread-pair. One relaxed counter barrier per iter.
__global__ __launch_bounds__(1024) void sinkhorn_kernel(const unsigned short* __restrict__ W,
                                                        float* __restrict__ Sp,
                                                        unsigned int* __restrict__ bar,
                                                        float* __restrict__ dist4) {
    int gid = blockIdx.x;
    int b = gid & 63, q = gid >> 6;
    const unsigned short* slab = W + (size_t)b * NN * MM + q * 128;

    __shared__ float    eu_s[NN];
    __shared__ unsigned eu_pk[NN / 2];
    __shared__ float    ev_f[128];
    __shared__ unsigned ev_pk[64];
    __shared__ float    part[16 * 132];
    __shared__ float    red[16];

    int t = threadIdx.x;
    int w = t >> 6, lane = t & 63, sub = lane >> 4, l16 = lane & 15;
    int c16 = t & 15, rgrp = t >> 4;

    if (t < 64)  ev_pk[t] = 0x3F803F80u;
    if (t < 128) ev_f[t] = 1.0f;
    __syncthreads();

    unsigned int* ctr = bar + b;
    const unsigned short* colbase = slab + c16 * 8;

    for (int it = 0; it < ITERS; ++it) {
        float* spb = Sp + (size_t)(it & 1) * (BB * NN * 4);

        // ---- phase A: partial row sums over own 128 cols, store direct ----
        uint4 evv = *(uint4*)&ev_pk[l16 * 4];
        #pragma unroll
        for (int sw = 0; sw < 8; ++sw) {
            int row = sw * 64 + w * 4 + sub;
            uint4 u = *(const uint4*)(slab + (size_t)row * MM + l16 * 8);
            float acc = 0.0f;
            acc = fdot2bf(u.x, evv.x, acc);
            acc = fdot2bf(u.y, evv.y, acc);
            acc = fdot2bf(u.z, evv.z, acc);
            acc = fdot2bf(u.w, evv.w, acc);
            acc += __shfl_xor(acc, 1, 64);
            acc += __shfl_xor(acc, 2, 64);
            acc += __shfl_xor(acc, 4, 64);
            acc += __shfl_xor(acc, 8, 64);
            if (l16 == 0)
                __hip_atomic_store(&spb[((size_t)b * NN + row) * 4 + q], acc,
                                   __ATOMIC_RELAXED, __HIP_MEMORY_SCOPE_AGENT);
        }

        // ---- prefetch phase-B W into VGPRs (hides L2 under the barrier) ----
        uint4 pa[4], pb[4];
        #pragma unroll
        for (int pp = 0; pp < 4; ++pp) {
            const unsigned short* r0 = colbase + (size_t)(2 * (rgrp + 64 * pp)) * MM;
            pa[pp] = *(const uint4*)(r0);
            pb[pp] = *(const uint4*)(r0 + MM);
        }

        __syncthreads();   // drains partial stores (vmcnt 0) before arrival add

        if (t == 0) {
            __hip_atomic_fetch_add(ctr, 1u, __ATOMIC_RELAXED, __HIP_MEMORY_SCOPE_AGENT);
            unsigned tgt = 4u * (unsigned)(it + 1);
            while (__hip_atomic_load(ctr, __ATOMIC_RELAXED, __HIP_MEMORY_SCOPE_AGENT) < tgt)
                __builtin_amdgcn_s_sleep(1);
        }
        __syncthreads();

        // ---- gather: rows (2t, 2t+1), 8 contiguous f32 -> eu pair + pack ----
        if (t < 256) {
            const float* g = spb + ((size_t)b * NN + 2 * t) * 4;
            float s0 = __hip_atomic_load(g + 0, __ATOMIC_RELAXED, __HIP_MEMORY_SCOPE_AGENT)
                     + __hip_atomic_load(g + 1, __ATOMIC_RELAXED, __HIP_MEMORY_SCOPE_AGENT)
                     + __hip_atomic_load(g + 2, __ATOMIC_RELAXED, __HIP_MEMORY_SCOPE_AGENT)
                     + __hip_atomic_load(g + 3, __ATOMIC_RELAXED, __HIP_MEMORY_SCOPE_AGENT);
            float s1 = __hip_atomic_load(g + 4, __ATOMIC_RELAXED, __HIP_MEMORY_SCOPE_AGENT)
                     + __hip_atomic_load(g + 5, __ATOMIC_RELAXED, __HIP_MEMORY_SCOPE_AGENT)
                     + __hip_atomic_load(g + 6, __ATOMIC_RELAXED, __HIP_MEMORY_SCOPE_AGENT)
                     + __hip_atomic_load(g + 7, __ATOMIC_RELAXED, __HIP_MEMORY_SCOPE_AGENT);
            float e0 = A_CONST / s0, e1 = A_CONST / s1;
            eu_s[2 * t]     = e0;
            eu_s[2 * t + 1] = e1;
            eu_pk[t] = pack2(e0, e1);
        }
        __syncthreads();

        // ---- phase B: T_j over own cols from prefetched W ----
        float a0 = 0, a1 = 0, a2 = 0, a3 = 0, a4 = 0, a5 = 0, a6 = 0, a7 = 0;
        #pragma unroll
        for (int pp = 0; pp < 4; ++pp) {
            unsigned ep = eu_pk[rgrp + 64 * pp];
            uint4 u = pa[pp], u2 = pb[pp];
            a0 = fdot2bf(__builtin_amdgcn_perm(u2.x, u.x, 0x05040100u), ep, a0);
            a1 = fdot2bf(__builtin_amdgcn_perm(u2.x, u.x, 0x07060302u), ep, a1);
            a2 = fdot2bf(__builtin_amdgcn_perm(u2.y, u.y, 0x05040100u), ep, a2);
            a3 = fdot2bf(__builtin_amdgcn_perm(u2.y, u.y, 0x07060302u), ep, a3);
            a4 = fdot2bf(__builtin_amdgcn_perm(u2.z, u.z, 0x05040100u), ep, a4);
            a5 = fdot2bf(__builtin_amdgcn_perm(u2.z, u.z, 0x07060302u), ep, a5);
            a6 = fdot2bf(__builtin_amdgcn_perm(u2.w, u.w, 0x05040100u), ep, a6);
            a7 = fdot2bf(__builtin_amdgcn_perm(u2.w, u.w, 0x07060302u), ep, a7);
        }
        // wave pre-reduction over the 4 sub-groups (same c16 within wave)
        a0 += __shfl_xor(a0, 16, 64); a0 += __shfl_xor(a0, 32, 64);
        a1 += __shfl_xor(a1, 16, 64); a1 += __shfl_xor(a1, 32, 64);
        a2 += __shfl_xor(a2, 16, 64); a2 += __shfl_xor(a2, 32, 64);
        a3 += __shfl_xor(a3, 16, 64); a3 += __shfl_xor(a3, 32, 64);
        a4 += __shfl_xor(a4, 16, 64); a4 += __shfl_xor(a4, 32, 64);
        a5 += __shfl_xor(a5, 16, 64); a5 += __shfl_xor(a5, 32, 64);
        a6 += __shfl_xor(a6, 16, 64); a6 += __shfl_xor(a6, 32, 64);
        a7 += __shfl_xor(a7, 16, 64); a7 += __shfl_xor(a7, 32, 64);
        if (lane < 16) {
            *(float4*)&part[w * 132 + c16 * 8]     = make_float4(a0, a1, a2, a3);
            *(float4*)&part[w * 132 + c16 * 8 + 4] = make_float4(a4, a5, a6, a7);
        }
        __syncthreads();

        if (t < 64) {
            float s0 = 0.0f, s1 = 0.0f;
            #pragma unroll
            for (int ww = 0; ww < 16; ++ww) {
                s0 += part[ww * 132 + 2 * t];
                s1 += part[ww * 132 + 2 * t + 1];
            }
            float e0 = B_CONST / s0, e1 = B_CONST / s1;
            ev_f[2 * t]     = e0;
            ev_f[2 * t + 1] = e1;
            ev_pk[t] = pack2(e0, e1);
        }
        __syncthreads();
    }

    // ---- fused distance partial over own cols ----
    float evr[8];
    #pragma unroll
    for (int k = 0; k < 8; ++k) evr[k] = ev_f[l16 * 8 + k];
    float dacc = 0.0f;
    #pragma unroll 2
    for (int sw = 0; sw < 8; ++sw) {
        int row = sw * 64 + w * 4 + sub;
        uint4 u = *(const uint4*)(slab + (size_t)row * MM + l16 * 8);
        float eu = eu_s[row];
        float w0 = bflo(u.x), w1 = bfhi(u.x), w2 = bflo(u.y), w3 = bfhi(u.y);
        float w4 = bflo(u.z), w5 = bfhi(u.z), w6 = bflo(u.w), w7 = bfhi(u.w);
        float s = w0 * __logf(w0) * evr[0] + w1 * __logf(w1) * evr[1]
                + w2 * __logf(w2) * evr[2] + w3 * __logf(w3) * evr[3]
                + w4 * __logf(w4) * evr[4] + w5 * __logf(w5) * evr[5]
                + w6 * __logf(w6) * evr[6] + w7 * __logf(w7) * evr[7];
        dacc += eu * s;
    }
    #pragma unroll
    for (int off = 32; off; off >>= 1) dacc += __shfl_xor(dacc, off, 64);
    if (lane == 0) red[w] = dacc;
    __syncthreads();
    if (t == 0) {
        float s = 0.0f;
        #pragma unroll
        for (int i = 0; i < 16; ++i) s += red[i];
        dist4[gid] = s;
    }
}

// ---------------- kernel 4: mean over 256 partials ----------------
__global__ __launch_bounds__(256) void mean_kernel(const float* __restrict__ dist4,
                                                   float* __restrict__ out) {
    __shared__ float red[4];
    int t = threadIdx.x;
    float v = dist4[t];
    #pragma unroll
    for (int off = 32; off; off >>= 1) v += __shfl_xor(v, off, 64);
    if ((t & 63) == 0) red[t >> 6] = v;
    __syncthreads();
    if (t == 0) out[0] = -SINK_EPS_F * (red[0] + red[1] + red[2] + red[3]) * (1.0f / 64.0f);
}

extern "C" void kernel_launch(void* const* d_in, const int* in_sizes, int n_in,
                              void* d_out, int out_size, void* d_ws, size_t ws_size,
                              hipStream_t stream) {
    const float* src = (const float*)d_in[0];
    const float* tgt = (const float*)d_in[1];
    char* ws = (char*)d_ws;

    float*          inv_ns = (float*)(ws);
    float*          inv_nt = (float*)(ws + 131072);
    unsigned short* W      = (unsigned short*)(ws + 262144);
    float*          Sp     = (float*)(ws + 262144 + 33554432);                 // 1 MB (2 bufs)
    float*          dist4  = (float*)(ws + 262144 + 33554432 + 1048576);
    unsigned int*   bar    = (unsigned int*)(ws + 262144 + 33554432 + 1048576 + 4096);
    float*          out    = (float*)d_out;

    hipMemsetAsync(bar, 0, 64 * sizeof(unsigned int), stream);

    hipLaunchKernelGGL(norm_kernel,      dim3(16384), dim3(256),  0, stream, src, tgt, inv_ns, inv_nt);
    hipLaunchKernelGGL(cost_mfma_kernel, dim3(1024),  dim3(256),  0, stream, src, tgt, inv_ns, inv_nt, W);
    hipLaunchKernelGGL(sinkhorn_kernel,  dim3(256),   dim3(1024), 0, stream, W, Sp, bar, dist4);
    hipLaunchKernelGGL(mean_kernel,      dim3(1),     dim3(256),  0, stream, dist4, out);
}

// Round 5
// 517.251 us; speedup vs baseline: 1.7303x; 1.7303x over previous
//
#include <hip/hip_runtime.h>
#include <hip/hip_bf16.h>
#include <cstdint>
#include <cstddef>

#define BB 64
#define NN 512
#define MM 512
#define DD 128

static constexpr float SINK_EPS_F = 0.05f;
static constexpr int   ITERS      = 80;
static constexpr float A_CONST    = 1.0f / 512.0f;
static constexpr float B_CONST    = 1.0f / 512.0f;

typedef __attribute__((ext_vector_type(8))) short bf16x8;
typedef __attribute__((ext_vector_type(4))) float f32x4;

__device__ __forceinline__ float bflo(unsigned u) { return __uint_as_float(u << 16); }
__device__ __forceinline__ float bfhi(unsigned u) { return __uint_as_float(u & 0xffff0000u); }

__device__ __forceinline__ float fdot2bf(unsigned a, unsigned b, float c) {
    asm("v_dot2_f32_bf16 %0, %1, %2, %0" : "+v"(c) : "v"(a), "v"(b));
    return c;
}
__device__ __forceinline__ unsigned short bfr(float x) {
    __hip_bfloat16 h = __float2bfloat16(x);
    return *reinterpret_cast<unsigned short*>(&h);
}
__device__ __forceinline__ unsigned pack2(float lo, float hi) {
    return (unsigned)bfr(lo) | ((unsigned)bfr(hi) << 16);
}
__device__ __forceinline__ uint2 pk4(float4 v) {
    uint2 r;
    r.x = (unsigned)bfr(v.x) | ((unsigned)bfr(v.y) << 16);
    r.y = (unsigned)bfr(v.z) | ((unsigned)bfr(v.w) << 16);
    return r;
}

// ---------------- kernel 1: row inverse norms ----------------
__global__ __launch_bounds__(256) void norm_kernel(const float* __restrict__ src,
                                                   const float* __restrict__ tgt,
                                                   float* __restrict__ inv_ns,
                                                   float* __restrict__ inv_nt) {
    int wave = (blockIdx.x * blockDim.x + threadIdx.x) >> 6;
    int lane = threadIdx.x & 63;
    const float* row;
    float* out;
    if (wave < BB * NN) { row = src + (size_t)wave * DD; out = inv_ns + wave; }
    else                { row = tgt + (size_t)(wave - BB * NN) * DD; out = inv_nt + (wave - BB * NN); }
    float2 v = ((const float2*)row)[lane];
    float s = v.x * v.x + v.y * v.y;
    #pragma unroll
    for (int off = 32; off; off >>= 1) s += __shfl_xor(s, off, 64);
    if (lane == 0) *out = 1.0f / fmaxf(sqrtf(s), 1e-12f);
}

// ---------------- kernel 2: MFMA bf16 cost GEMM -> W = exp(-C/eps) ----------------
#define RS 136

__global__ __launch_bounds__(256) void cost_mfma_kernel(const float* __restrict__ S,
                                                        const float* __restrict__ T,
                                                        const float* __restrict__ inv_ns,
                                                        const float* __restrict__ inv_nt,
                                                        unsigned short* __restrict__ W) {
    __shared__ unsigned short sA[128 * RS];
    __shared__ unsigned short sB[128 * RS];
    int bid = blockIdx.x;
    int b  = bid >> 4;
    int i0 = ((bid >> 2) & 3) * 128;
    int j0 = (bid & 3) * 128;
    int t  = threadIdx.x;

    {
        int r = t >> 1, h = t & 1;
        int gra = b * NN + i0 + r;
        int grb = b * MM + j0 + r;
        float sca = inv_ns[gra], scb = inv_nt[grb];
        const float4* pS = (const float4*)(S + (size_t)gra * DD + h * 64);
        const float4* pT = (const float4*)(T + (size_t)grb * DD + h * 64);
        unsigned short* dA = &sA[r * RS + h * 64];
        unsigned short* dB = &sB[r * RS + h * 64];
        #pragma unroll
        for (int c4 = 0; c4 < 16; ++c4) {
            float4 v = pS[c4];
            v.x *= sca; v.y *= sca; v.z *= sca; v.w *= sca;
            *(uint2*)&dA[c4 * 4] = pk4(v);
            float4 u = pT[c4];
            u.x *= scb; u.y *= scb; u.z *= scb; u.w *= scb;
            *(uint2*)&dB[c4 * 4] = pk4(u);
        }
    }
    __syncthreads();

    int l = t & 63, w = t >> 6;
    int wr = (w >> 1) * 64, wc = (w & 1) * 64;
    int fr = l & 15, fo = (l >> 4) * 8;

    f32x4 acc[4][4];
    #pragma unroll
    for (int m = 0; m < 4; ++m)
        #pragma unroll
        for (int n = 0; n < 4; ++n)
            acc[m][n] = (f32x4){0.f, 0.f, 0.f, 0.f};

    #pragma unroll
    for (int kk = 0; kk < 4; ++kk) {
        bf16x8 af[4], bfv[4];
        #pragma unroll
        for (int m = 0; m < 4; ++m)
            af[m] = *(bf16x8*)&sA[(wr + m * 16 + fr) * RS + kk * 32 + fo];
        #pragma unroll
        for (int n = 0; n < 4; ++n)
            bfv[n] = *(bf16x8*)&sB[(wc + n * 16 + fr) * RS + kk * 32 + fo];
        #pragma unroll
        for (int m = 0; m < 4; ++m)
            #pragma unroll
            for (int n = 0; n < 4; ++n)
                acc[m][n] = __builtin_amdgcn_mfma_f32_16x16x32_bf16(af[m], bfv[n], acc[m][n], 0, 0, 0);
    }

    int rb = (l >> 4) * 4;
    #pragma unroll
    for (int m = 0; m < 4; ++m) {
        #pragma unroll
        for (int n = 0; n < 4; ++n) {
            #pragma unroll
            for (int r = 0; r < 4; ++r) {
                int gi = b * NN + i0 + wr + m * 16 + rb + r;
                int gj = j0 + wc + n * 16 + fr;
                float c = acc[m][n][r];
                float cost = fmaxf(2.0f - 2.0f * c, 0.0f);
                W[(size_t)gi * MM + gj] = bfr(__expf(-20.0f * cost));
            }
        }
    }
}

// ---------------- kernel 3: column-slab Sinkhorn ----------------
// Block (b,q) owns W[b][:, 128q..128q+128). Partials in Sp[buf][b*4+q][row]
// (contiguous 2KB store staged via LDS). One relaxed counter barrier per iter.
// Phase-B W prefetched into VGPRs before the barrier wait.
__global__ __launch_bounds__(1024) void sinkhorn_kernel(const unsigned short* __restrict__ W,
                                                        float* __restrict__ Sp,
                                                        unsigned int* __restrict__ bar,
                                                        float* __restrict__ dist4) {
    int gid = blockIdx.x;
    int b = gid & 63, q = gid >> 6;
    const unsigned short* slab = W + (size_t)b * NN * MM + q * 128;

    __shared__ float    eu_s[NN];
    __shared__ unsigned eu_pk[NN / 2];
    __shared__ float    s_row[NN];
    __shared__ float    ev_f[128];
    __shared__ unsigned ev_pk[64];
    __shared__ float    part[16 * 132];
    __shared__ float    red[16];

    int t = threadIdx.x;
    int w = t >> 6, lane = t & 63, sub = lane >> 4, l16 = lane & 15;
    int c16 = t & 15, rgrp = t >> 4;

    if (t < 64)  ev_pk[t] = 0x3F803F80u;
    if (t < 128) ev_f[t] = 1.0f;
    __syncthreads();

    unsigned int* ctr = bar + b * 16;        // 64B-separated counters
    const unsigned short* colbase = slab + c16 * 8;

    for (int it = 0; it < ITERS; ++it) {
        float* spb = Sp + (size_t)(it & 1) * (BB * 4 * NN);

        // ---- phase A: load all 8 W vectors first (8-deep MLP), then reduce ----
        uint4 evv = *(uint4*)&ev_pk[l16 * 4];
        uint4 wv[8];
        #pragma unroll
        for (int sw = 0; sw < 8; ++sw) {
            int row = sw * 64 + w * 4 + sub;
            wv[sw] = *(const uint4*)(slab + (size_t)row * MM + l16 * 8);
        }
        #pragma unroll
        for (int sw = 0; sw < 8; ++sw) {
            int row = sw * 64 + w * 4 + sub;
            float acc = 0.0f;
            acc = fdot2bf(wv[sw].x, evv.x, acc);
            acc = fdot2bf(wv[sw].y, evv.y, acc);
            acc = fdot2bf(wv[sw].z, evv.z, acc);
            acc = fdot2bf(wv[sw].w, evv.w, acc);
            acc += __shfl_xor(acc, 1, 64);
            acc += __shfl_xor(acc, 2, 64);
            acc += __shfl_xor(acc, 4, 64);
            acc += __shfl_xor(acc, 8, 64);
            if (l16 == 0) s_row[row] = acc;
        }
        __syncthreads();

        // ---- prefetch phase-B W into VGPRs (completes under the barrier wait) ----
        uint4 pa[4], pb[4];
        #pragma unroll
        for (int pp = 0; pp < 4; ++pp) {
            const unsigned short* r0 = colbase + (size_t)(2 * (rgrp + 64 * pp)) * MM;
            pa[pp] = *(const uint4*)(r0);
            pb[pp] = *(const uint4*)(r0 + MM);
        }

        // ---- contiguous UC partial store (2KB per block) ----
        if (t < NN)
            __hip_atomic_store(&spb[((size_t)b * 4 + q) * NN + t], s_row[t],
                               __ATOMIC_RELAXED, __HIP_MEMORY_SCOPE_AGENT);
        __syncthreads();   // drains vmcnt(0): partials visible before arrival add

        if (t == 0) {
            __hip_atomic_fetch_add(ctr, 1u, __ATOMIC_RELAXED, __HIP_MEMORY_SCOPE_AGENT);
            unsigned tgt = 4u * (unsigned)(it + 1);
            while (__hip_atomic_load(ctr, __ATOMIC_RELAXED, __HIP_MEMORY_SCOPE_AGENT) < tgt)
                __builtin_amdgcn_s_sleep(1);
        }
        __syncthreads();

        // ---- fused gather + eu + pack: rows (2t, 2t+1) via 8B atomic loads ----
        if (t < 256) {
            const unsigned long long* g =
                (const unsigned long long*)(spb + (size_t)b * 4 * NN + 2 * t);
            unsigned long long u0 = __hip_atomic_load(g,                 __ATOMIC_RELAXED, __HIP_MEMORY_SCOPE_AGENT);
            unsigned long long u1 = __hip_atomic_load(g + NN / 2,        __ATOMIC_RELAXED, __HIP_MEMORY_SCOPE_AGENT);
            unsigned long long u2 = __hip_atomic_load(g + NN,            __ATOMIC_RELAXED, __HIP_MEMORY_SCOPE_AGENT);
            unsigned long long u3 = __hip_atomic_load(g + 3 * (NN / 2),  __ATOMIC_RELAXED, __HIP_MEMORY_SCOPE_AGENT);
            float2 f0 = *(float2*)&u0, f1 = *(float2*)&u1, f2 = *(float2*)&u2, f3 = *(float2*)&u3;
            float s0 = f0.x + f1.x + f2.x + f3.x;
            float s1 = f0.y + f1.y + f2.y + f3.y;
            float e0 = A_CONST / s0, e1 = A_CONST / s1;
            eu_s[2 * t]     = e0;
            eu_s[2 * t + 1] = e1;
            eu_pk[t] = pack2(e0, e1);
        }
        __syncthreads();

        // ---- phase B: T_j over own cols from prefetched W ----
        float a0 = 0, a1 = 0, a2 = 0, a3 = 0, a4 = 0, a5 = 0, a6 = 0, a7 = 0;
        #pragma unroll
        for (int pp = 0; pp < 4; ++pp) {
            unsigned ep = eu_pk[rgrp + 64 * pp];
            uint4 u = pa[pp], u2 = pb[pp];
            a0 = fdot2bf(__builtin_amdgcn_perm(u2.x, u.x, 0x05040100u), ep, a0);
            a1 = fdot2bf(__builtin_amdgcn_perm(u2.x, u.x, 0x07060302u), ep, a1);
            a2 = fdot2bf(__builtin_amdgcn_perm(u2.y, u.y, 0x05040100u), ep, a2);
            a3 = fdot2bf(__builtin_amdgcn_perm(u2.y, u.y, 0x07060302u), ep, a3);
            a4 = fdot2bf(__builtin_amdgcn_perm(u2.z, u.z, 0x05040100u), ep, a4);
            a5 = fdot2bf(__builtin_amdgcn_perm(u2.z, u.z, 0x07060302u), ep, a5);
            a6 = fdot2bf(__builtin_amdgcn_perm(u2.w, u.w, 0x05040100u), ep, a6);
            a7 = fdot2bf(__builtin_amdgcn_perm(u2.w, u.w, 0x07060302u), ep, a7);
        }
        a0 += __shfl_xor(a0, 16, 64); a0 += __shfl_xor(a0, 32, 64);
        a1 += __shfl_xor(a1, 16, 64); a1 += __shfl_xor(a1, 32, 64);
        a2 += __shfl_xor(a2, 16, 64); a2 += __shfl_xor(a2, 32, 64);
        a3 += __shfl_xor(a3, 16, 64); a3 += __shfl_xor(a3, 32, 64);
        a4 += __shfl_xor(a4, 16, 64); a4 += __shfl_xor(a4, 32, 64);
        a5 += __shfl_xor(a5, 16, 64); a5 += __shfl_xor(a5, 32, 64);
        a6 += __shfl_xor(a6, 16, 64); a6 += __shfl_xor(a6, 32, 64);
        a7 += __shfl_xor(a7, 16, 64); a7 += __shfl_xor(a7, 32, 64);
        if (lane < 16) {
            *(float4*)&part[w * 132 + c16 * 8]     = make_float4(a0, a1, a2, a3);
            *(float4*)&part[w * 132 + c16 * 8 + 4] = make_float4(a4, a5, a6, a7);
        }
        __syncthreads();

        if (t < 64) {
            float s0 = 0.0f, s1 = 0.0f;
            #pragma unroll
            for (int ww = 0; ww < 16; ++ww) {
                s0 += part[ww * 132 + 2 * t];
                s1 += part[ww * 132 + 2 * t + 1];
            }
            float e0 = B_CONST / s0, e1 = B_CONST / s1;
            ev_f[2 * t]     = e0;
            ev_f[2 * t + 1] = e1;
            ev_pk[t] = pack2(e0, e1);
        }
        __syncthreads();
    }

    // ---- fused distance partial over own cols ----
    float evr[8];
    #pragma unroll
    for (int k = 0; k < 8; ++k) evr[k] = ev_f[l16 * 8 + k];
    float dacc = 0.0f;
    #pragma unroll 2
    for (int sw = 0; sw < 8; ++sw) {
        int row = sw * 64 + w * 4 + sub;
        uint4 u = *(const uint4*)(slab + (size_t)row * MM + l16 * 8);
        float eu = eu_s[row];
        float w0 = bflo(u.x), w1 = bfhi(u.x), w2 = bflo(u.y), w3 = bfhi(u.y);
        float w4 = bflo(u.z), w5 = bfhi(u.z), w6 = bflo(u.w), w7 = bfhi(u.w);
        float s = w0 * __logf(w0) * evr[0] + w1 * __logf(w1) * evr[1]
                + w2 * __logf(w2) * evr[2] + w3 * __logf(w3) * evr[3]
                + w4 * __logf(w4) * evr[4] + w5 * __logf(w5) * evr[5]
                + w6 * __logf(w6) * evr[6] + w7 * __logf(w7) * evr[7];
        dacc += eu * s;
    }
    #pragma unroll
    for (int off = 32; off; off >>= 1) dacc += __shfl_xor(dacc, off, 64);
    if (lane == 0) red[w] = dacc;
    __syncthreads();
    if (t == 0) {
        float s = 0.0f;
        #pragma unroll
        for (int i = 0; i < 16; ++i) s += red[i];
        dist4[gid] = s;
    }
}

// ---------------- kernel 4: mean over 256 partials ----------------
__global__ __launch_bounds__(256) void mean_kernel(const float* __restrict__ dist4,
                                                   float* __restrict__ out) {
    __shared__ float red[4];
    int t = threadIdx.x;
    float v = dist4[t];
    #pragma unroll
    for (int off = 32; off; off >>= 1) v += __shfl_xor(v, off, 64);
    if ((t & 63) == 0) red[t >> 6] = v;
    __syncthreads();
    if (t == 0) out[0] = -SINK_EPS_F * (red[0] + red[1] + red[2] + red[3]) * (1.0f / 64.0f);
}

extern "C" void kernel_launch(void* const* d_in, const int* in_sizes, int n_in,
                              void* d_out, int out_size, void* d_ws, size_t ws_size,
                              hipStream_t stream) {
    const float* src = (const float*)d_in[0];
    const float* tgt = (const float*)d_in[1];
    char* ws = (char*)d_ws;

    float*          inv_ns = (float*)(ws);
    float*          inv_nt = (float*)(ws + 131072);
    unsigned short* W      = (unsigned short*)(ws + 262144);
    float*          Sp     = (float*)(ws + 262144 + 33554432);                 // 1 MB (2 bufs)
    float*          dist4  = (float*)(ws + 262144 + 33554432 + 1048576);
    unsigned int*   bar    = (unsigned int*)(ws + 262144 + 33554432 + 1048576 + 4096);
    float*          out    = (float*)d_out;

    hipMemsetAsync(bar, 0, 64 * 16 * sizeof(unsigned int), stream);

    hipLaunchKernelGGL(norm_kernel,      dim3(16384), dim3(256),  0, stream, src, tgt, inv_ns, inv_nt);
    hipLaunchKernelGGL(cost_mfma_kernel, dim3(1024),  dim3(256),  0, stream, src, tgt, inv_ns, inv_nt, W);
    hipLaunchKernelGGL(sinkhorn_kernel,  dim3(256),   dim3(1024), 0, stream, W, Sp, bar, dist4);
    hipLaunchKernelGGL(mean_kernel,      dim3(1),     dim3(256),  0, stream, dist4, out);
}

// Round 6
// 402.474 us; speedup vs baseline: 2.2237x; 1.2852x over previous
//
#include <hip/hip_runtime.h>
#include <hip/hip_bf16.h>
#include <cstdint>
#include <cstddef>

#define BB 64
#define NN 512
#define MM 512
#define DD 128

static constexpr float SINK_EPS_F = 0.05f;
static constexpr int   ITERS      = 80;
static constexpr float A_CONST    = 1.0f / 512.0f;
static constexpr float B_CONST    = 1.0f / 512.0f;

typedef __attribute__((ext_vector_type(8))) short bf16x8;
typedef __attribute__((ext_vector_type(4))) float f32x4;

__device__ __forceinline__ float bflo(unsigned u) { return __uint_as_float(u << 16); }
__device__ __forceinline__ float bfhi(unsigned u) { return __uint_as_float(u & 0xffff0000u); }

__device__ __forceinline__ float fdot2bf(unsigned a, unsigned b, float c) {
    asm("v_dot2_f32_bf16 %0, %1, %2, %0" : "+v"(c) : "v"(a), "v"(b));
    return c;
}
__device__ __forceinline__ unsigned short bfr(float x) {
    __hip_bfloat16 h = __float2bfloat16(x);
    return *reinterpret_cast<unsigned short*>(&h);
}
__device__ __forceinline__ unsigned pack2(float lo, float hi) {
    return (unsigned)bfr(lo) | ((unsigned)bfr(hi) << 16);
}
__device__ __forceinline__ uint2 pk4(float4 v) {
    uint2 r;
    r.x = (unsigned)bfr(v.x) | ((unsigned)bfr(v.y) << 16);
    r.y = (unsigned)bfr(v.z) | ((unsigned)bfr(v.w) << 16);
    return r;
}

// ---------------- kernel 1: row inverse norms ----------------
__global__ __launch_bounds__(256) void norm_kernel(const float* __restrict__ src,
                                                   const float* __restrict__ tgt,
                                                   float* __restrict__ inv_ns,
                                                   float* __restrict__ inv_nt) {
    int wave = (blockIdx.x * blockDim.x + threadIdx.x) >> 6;
    int lane = threadIdx.x & 63;
    const float* row;
    float* out;
    if (wave < BB * NN) { row = src + (size_t)wave * DD; out = inv_ns + wave; }
    else                { row = tgt + (size_t)(wave - BB * NN) * DD; out = inv_nt + (wave - BB * NN); }
    float2 v = ((const float2*)row)[lane];
    float s = v.x * v.x + v.y * v.y;
    #pragma unroll
    for (int off = 32; off; off >>= 1) s += __shfl_xor(s, off, 64);
    if (lane == 0) *out = 1.0f / fmaxf(sqrtf(s), 1e-12f);
}

// ---------------- kernel 2: MFMA bf16 cost GEMM -> W = exp(-C/eps) ----------------
#define RS 136

__global__ __launch_bounds__(256) void cost_mfma_kernel(const float* __restrict__ S,
                                                        const float* __restrict__ T,
                                                        const float* __restrict__ inv_ns,
                                                        const float* __restrict__ inv_nt,
                                                        unsigned short* __restrict__ W) {
    __shared__ unsigned short sA[128 * RS];
    __shared__ unsigned short sB[128 * RS];
    int bid = blockIdx.x;
    int b  = bid >> 4;
    int i0 = ((bid >> 2) & 3) * 128;
    int j0 = (bid & 3) * 128;
    int t  = threadIdx.x;

    {
        int r = t >> 1, h = t & 1;
        int gra = b * NN + i0 + r;
        int grb = b * MM + j0 + r;
        float sca = inv_ns[gra], scb = inv_nt[grb];
        const float4* pS = (const float4*)(S + (size_t)gra * DD + h * 64);
        const float4* pT = (const float4*)(T + (size_t)grb * DD + h * 64);
        unsigned short* dA = &sA[r * RS + h * 64];
        unsigned short* dB = &sB[r * RS + h * 64];
        #pragma unroll
        for (int c4 = 0; c4 < 16; ++c4) {
            float4 v = pS[c4];
            v.x *= sca; v.y *= sca; v.z *= sca; v.w *= sca;
            *(uint2*)&dA[c4 * 4] = pk4(v);
            float4 u = pT[c4];
            u.x *= scb; u.y *= scb; u.z *= scb; u.w *= scb;
            *(uint2*)&dB[c4 * 4] = pk4(u);
        }
    }
    __syncthreads();

    int l = t & 63, w = t >> 6;
    int wr = (w >> 1) * 64, wc = (w & 1) * 64;
    int fr = l & 15, fo = (l >> 4) * 8;

    f32x4 acc[4][4];
    #pragma unroll
    for (int m = 0; m < 4; ++m)
        #pragma unroll
        for (int n = 0; n < 4; ++n)
            acc[m][n] = (f32x4){0.f, 0.f, 0.f, 0.f};

    #pragma unroll
    for (int kk = 0; kk < 4; ++kk) {
        bf16x8 af[4], bfv[4];
        #pragma unroll
        for (int m = 0; m < 4; ++m)
            af[m] = *(bf16x8*)&sA[(wr + m * 16 + fr) * RS + kk * 32 + fo];
        #pragma unroll
        for (int n = 0; n < 4; ++n)
            bfv[n] = *(bf16x8*)&sB[(wc + n * 16 + fr) * RS + kk * 32 + fo];
        #pragma unroll
        for (int m = 0; m < 4; ++m)
            #pragma unroll
            for (int n = 0; n < 4; ++n)
                acc[m][n] = __builtin_amdgcn_mfma_f32_16x16x32_bf16(af[m], bfv[n], acc[m][n], 0, 0, 0);
    }

    int rb = (l >> 4) * 4;
    #pragma unroll
    for (int m = 0; m < 4; ++m) {
        #pragma unroll
        for (int n = 0; n < 4; ++n) {
            #pragma unroll
            for (int r = 0; r < 4; ++r) {
                int gi = b * NN + i0 + wr + m * 16 + rb + r;
                int gj = j0 + wc + n * 16 + fr;
                float c = acc[m][n][r];
                float cost = fmaxf(2.0f - 2.0f * c, 0.0f);
                W[(size_t)gi * MM + gj] = bfr(__expf(-20.0f * cost));
            }
        }
    }
}

// ---------------- kernel 3: register-resident column-slab Sinkhorn ----------------
// Block (b,q) owns W[b][:, 128q..128q+128) ENTIRELY IN VGPRs (32/thread):
// thread (g=t>>4, c16=t&15) holds rows {2(g+64pp), +1} x cols [8c16, 8c16+8).
// Phase A: dot2 over own 8 cols + shfl reduce over the 16-lane col-group;
// leaders store coalesced 8B UC partials. One relaxed counter barrier/iter.
// Phase B: perm row-pairs, dot2 with eu pairs. ev never leaves the block.
__global__ __launch_bounds__(1024) void sinkhorn_kernel(const unsigned short* __restrict__ W,
                                                        float* __restrict__ Sp,
                                                        unsigned int* __restrict__ bar,
                                                        float* __restrict__ dist4) {
    int gid = blockIdx.x;
    int b = gid & 63, q = gid >> 6;
    const unsigned short* slab = W + (size_t)b * NN * MM + q * 128;

    __shared__ float    eu_s[NN];
    __shared__ unsigned eu_pk[NN / 2];
    __shared__ float    ev_f[128];
    __shared__ unsigned ev_pk[64];
    __shared__ float    part[16 * 132];
    __shared__ float    red[16];

    int t = threadIdx.x;
    int w = t >> 6, lane = t & 63;
    int g = t >> 4, c16 = t & 15;

    // ---- one-time load: whole slab into registers ----
    uint4 pa[4], pb[4];
    #pragma unroll
    for (int pp = 0; pp < 4; ++pp) {
        const unsigned short* r0 = slab + (size_t)(2 * (g + 64 * pp)) * MM + c16 * 8;
        pa[pp] = *(const uint4*)r0;
        pb[pp] = *(const uint4*)(r0 + MM);
    }

    if (t < 64)  ev_pk[t] = 0x3F803F80u;
    if (t < 128) ev_f[t] = 1.0f;
    __syncthreads();

    unsigned int* ctr = bar + b * 16;

    for (int it = 0; it < ITERS; ++it) {
        float* spb = Sp + (size_t)(it & 1) * (BB * 4 * NN);

        // ---- phase A: row sums from resident registers ----
        uint4 evv = *(uint4*)&ev_pk[c16 * 4];
        #pragma unroll
        for (int pp = 0; pp < 4; ++pp) {
            float ra = 0.0f, rb2 = 0.0f;
            ra  = fdot2bf(pa[pp].x, evv.x, ra);
            ra  = fdot2bf(pa[pp].y, evv.y, ra);
            ra  = fdot2bf(pa[pp].z, evv.z, ra);
            ra  = fdot2bf(pa[pp].w, evv.w, ra);
            rb2 = fdot2bf(pb[pp].x, evv.x, rb2);
            rb2 = fdot2bf(pb[pp].y, evv.y, rb2);
            rb2 = fdot2bf(pb[pp].z, evv.z, rb2);
            rb2 = fdot2bf(pb[pp].w, evv.w, rb2);
            ra  += __shfl_xor(ra, 1, 64);  ra  += __shfl_xor(ra, 2, 64);
            ra  += __shfl_xor(ra, 4, 64);  ra  += __shfl_xor(ra, 8, 64);
            rb2 += __shfl_xor(rb2, 1, 64); rb2 += __shfl_xor(rb2, 2, 64);
            rb2 += __shfl_xor(rb2, 4, 64); rb2 += __shfl_xor(rb2, 8, 64);
            if (c16 == 0) {
                int p = g + 64 * pp;
                float2 v = make_float2(ra, rb2);
                __hip_atomic_store((unsigned long long*)&spb[((size_t)b * 4 + q) * NN + 2 * p],
                                   *(unsigned long long*)&v,
                                   __ATOMIC_RELAXED, __HIP_MEMORY_SCOPE_AGENT);
            }
        }
        __syncthreads();   // drains vmcnt(0): partials visible before arrival add

        if (t == 0) {
            __hip_atomic_fetch_add(ctr, 1u, __ATOMIC_RELAXED, __HIP_MEMORY_SCOPE_AGENT);
            unsigned tgt = 4u * (unsigned)(it + 1);
            while (__hip_atomic_load(ctr, __ATOMIC_RELAXED, __HIP_MEMORY_SCOPE_AGENT) < tgt)
                __builtin_amdgcn_s_sleep(1);
        }
        __syncthreads();

        // ---- fused gather + eu + pack: rows (2t, 2t+1) via 8B atomic loads ----
        if (t < 256) {
            const unsigned long long* gp =
                (const unsigned long long*)(spb + (size_t)b * 4 * NN + 2 * t);
            unsigned long long u0 = __hip_atomic_load(gp,                __ATOMIC_RELAXED, __HIP_MEMORY_SCOPE_AGENT);
            unsigned long long u1 = __hip_atomic_load(gp + NN / 2,       __ATOMIC_RELAXED, __HIP_MEMORY_SCOPE_AGENT);
            unsigned long long u2 = __hip_atomic_load(gp + NN,           __ATOMIC_RELAXED, __HIP_MEMORY_SCOPE_AGENT);
            unsigned long long u3 = __hip_atomic_load(gp + 3 * (NN / 2), __ATOMIC_RELAXED, __HIP_MEMORY_SCOPE_AGENT);
            float2 f0 = *(float2*)&u0, f1 = *(float2*)&u1, f2 = *(float2*)&u2, f3 = *(float2*)&u3;
            float s0 = f0.x + f1.x + f2.x + f3.x;
            float s1 = f0.y + f1.y + f2.y + f3.y;
            float e0 = A_CONST / s0, e1 = A_CONST / s1;
            eu_s[2 * t]     = e0;
            eu_s[2 * t + 1] = e1;
            eu_pk[t] = pack2(e0, e1);
        }
        __syncthreads();

        // ---- phase B: col sums from resident registers ----
        float a0 = 0, a1 = 0, a2 = 0, a3 = 0, a4 = 0, a5 = 0, a6 = 0, a7 = 0;
        #pragma unroll
        for (int pp = 0; pp < 4; ++pp) {
            unsigned ep = eu_pk[g + 64 * pp];
            uint4 u = pa[pp], u2 = pb[pp];
            a0 = fdot2bf(__builtin_amdgcn_perm(u2.x, u.x, 0x05040100u), ep, a0);
            a1 = fdot2bf(__builtin_amdgcn_perm(u2.x, u.x, 0x07060302u), ep, a1);
            a2 = fdot2bf(__builtin_amdgcn_perm(u2.y, u.y, 0x05040100u), ep, a2);
            a3 = fdot2bf(__builtin_amdgcn_perm(u2.y, u.y, 0x07060302u), ep, a3);
            a4 = fdot2bf(__builtin_amdgcn_perm(u2.z, u.z, 0x05040100u), ep, a4);
            a5 = fdot2bf(__builtin_amdgcn_perm(u2.z, u.z, 0x07060302u), ep, a5);
            a6 = fdot2bf(__builtin_amdgcn_perm(u2.w, u.w, 0x05040100u), ep, a6);
            a7 = fdot2bf(__builtin_amdgcn_perm(u2.w, u.w, 0x07060302u), ep, a7);
        }
        a0 += __shfl_xor(a0, 16, 64); a0 += __shfl_xor(a0, 32, 64);
        a1 += __shfl_xor(a1, 16, 64); a1 += __shfl_xor(a1, 32, 64);
        a2 += __shfl_xor(a2, 16, 64); a2 += __shfl_xor(a2, 32, 64);
        a3 += __shfl_xor(a3, 16, 64); a3 += __shfl_xor(a3, 32, 64);
        a4 += __shfl_xor(a4, 16, 64); a4 += __shfl_xor(a4, 32, 64);
        a5 += __shfl_xor(a5, 16, 64); a5 += __shfl_xor(a5, 32, 64);
        a6 += __shfl_xor(a6, 16, 64); a6 += __shfl_xor(a6, 32, 64);
        a7 += __shfl_xor(a7, 16, 64); a7 += __shfl_xor(a7, 32, 64);
        if (lane < 16) {
            *(float4*)&part[w * 132 + c16 * 8]     = make_float4(a0, a1, a2, a3);
            *(float4*)&part[w * 132 + c16 * 8 + 4] = make_float4(a4, a5, a6, a7);
        }
        __syncthreads();

        if (t < 64) {
            float s0 = 0.0f, s1 = 0.0f;
            #pragma unroll
            for (int ww = 0; ww < 16; ++ww) {
                s0 += part[ww * 132 + 2 * t];
                s1 += part[ww * 132 + 2 * t + 1];
            }
            float e0 = B_CONST / s0, e1 = B_CONST / s1;
            ev_f[2 * t]     = e0;
            ev_f[2 * t + 1] = e1;
            ev_pk[t] = pack2(e0, e1);
        }
        __syncthreads();
    }

    // ---- fused distance partial from resident registers ----
    float evr[8];
    #pragma unroll
    for (int k = 0; k < 8; ++k) evr[k] = ev_f[c16 * 8 + k];
    float dacc = 0.0f;
    #pragma unroll
    for (int pp = 0; pp < 4; ++pp) {
        int p = g + 64 * pp;
        float euA = eu_s[2 * p], euB = eu_s[2 * p + 1];
        uint4 u = pa[pp], u2 = pb[pp];
        {
            float w0 = bflo(u.x), w1 = bfhi(u.x), w2 = bflo(u.y), w3 = bfhi(u.y);
            float w4 = bflo(u.z), w5 = bfhi(u.z), w6 = bflo(u.w), w7 = bfhi(u.w);
            float s = w0 * __logf(w0) * evr[0] + w1 * __logf(w1) * evr[1]
                    + w2 * __logf(w2) * evr[2] + w3 * __logf(w3) * evr[3]
                    + w4 * __logf(w4) * evr[4] + w5 * __logf(w5) * evr[5]
                    + w6 * __logf(w6) * evr[6] + w7 * __logf(w7) * evr[7];
            dacc += euA * s;
        }
        {
            float w0 = bflo(u2.x), w1 = bfhi(u2.x), w2 = bflo(u2.y), w3 = bfhi(u2.y);
            float w4 = bflo(u2.z), w5 = bfhi(u2.z), w6 = bflo(u2.w), w7 = bfhi(u2.w);
            float s = w0 * __logf(w0) * evr[0] + w1 * __logf(w1) * evr[1]
                    + w2 * __logf(w2) * evr[2] + w3 * __logf(w3) * evr[3]
                    + w4 * __logf(w4) * evr[4] + w5 * __logf(w5) * evr[5]
                    + w6 * __logf(w6) * evr[6] + w7 * __logf(w7) * evr[7];
            dacc += euB * s;
        }
    }
    #pragma unroll
    for (int off = 32; off; off >>= 1) dacc += __shfl_xor(dacc, off, 64);
    if (lane == 0) red[w] = dacc;
    __syncthreads();
    if (t == 0) {
        float s = 0.0f;
        #pragma unroll
        for (int i = 0; i < 16; ++i) s += red[i];
        dist4[gid] = s;
    }
}

// ---------------- kernel 4: mean over 256 partials ----------------
__global__ __launch_bounds__(256) void mean_kernel(const float* __restrict__ dist4,
                                                   float* __restrict__ out) {
    __shared__ float red[4];
    int t = threadIdx.x;
    float v = dist4[t];
    #pragma unroll
    for (int off = 32; off; off >>= 1) v += __shfl_xor(v, off, 64);
    if ((t & 63) == 0) red[t >> 6] = v;
    __syncthreads();
    if (t == 0) out[0] = -SINK_EPS_F * (red[0] + red[1] + red[2] + red[3]) * (1.0f / 64.0f);
}

extern "C" void kernel_launch(void* const* d_in, const int* in_sizes, int n_in,
                              void* d_out, int out_size, void* d_ws, size_t ws_size,
                              hipStream_t stream) {
    const float* src = (const float*)d_in[0];
    const float* tgt = (const float*)d_in[1];
    char* ws = (char*)d_ws;

    float*          inv_ns = (float*)(ws);
    float*          inv_nt = (float*)(ws + 131072);
    unsigned short* W      = (unsigned short*)(ws + 262144);
    float*          Sp     = (float*)(ws + 262144 + 33554432);                 // 1 MB (2 bufs)
    float*          dist4  = (float*)(ws + 262144 + 33554432 + 1048576);
    unsigned int*   bar    = (unsigned int*)(ws + 262144 + 33554432 + 1048576 + 4096);
    float*          out    = (float*)d_out;

    hipMemsetAsync(bar, 0, 64 * 16 * sizeof(unsigned int), stream);

    hipLaunchKernelGGL(norm_kernel,      dim3(16384), dim3(256),  0, stream, src, tgt, inv_ns, inv_nt);
    hipLaunchKernelGGL(cost_mfma_kernel, dim3(1024),  dim3(256),  0, stream, src, tgt, inv_ns, inv_nt, W);
    hipLaunchKernelGGL(sinkhorn_kernel,  dim3(256),   dim3(1024), 0, stream, W, Sp, bar, dist4);
    hipLaunchKernelGGL(mean_kernel,      dim3(1),     dim3(256),  0, stream, dist4, out);
}

// Round 7
// 396.191 us; speedup vs baseline: 2.2590x; 1.0159x over previous
//
#include <hip/hip_runtime.h>
#include <hip/hip_bf16.h>
#include <cstdint>
#include <cstddef>

#define BB 64
#define NN 512
#define MM 512
#define DD 128

static constexpr float SINK_EPS_F = 0.05f;
static constexpr int   ITERS      = 80;
static constexpr float A_CONST    = 1.0f / 512.0f;
static constexpr float B_CONST    = 1.0f / 512.0f;

typedef __attribute__((ext_vector_type(8))) short bf16x8;
typedef __attribute__((ext_vector_type(4))) float f32x4;

__device__ __forceinline__ float bflo(unsigned u) { return __uint_as_float(u << 16); }
__device__ __forceinline__ float bfhi(unsigned u) { return __uint_as_float(u & 0xffff0000u); }

__device__ __forceinline__ float fdot2bf(unsigned a, unsigned b, float c) {
    asm("v_dot2_f32_bf16 %0, %1, %2, %0" : "+v"(c) : "v"(a), "v"(b));
    return c;
}
__device__ __forceinline__ unsigned short bfr(float x) {
    __hip_bfloat16 h = __float2bfloat16(x);
    return *reinterpret_cast<unsigned short*>(&h);
}
__device__ __forceinline__ unsigned pack2(float lo, float hi) {
    return (unsigned)bfr(lo) | ((unsigned)bfr(hi) << 16);
}
__device__ __forceinline__ uint2 pk4(float4 v) {
    uint2 r;
    r.x = (unsigned)bfr(v.x) | ((unsigned)bfr(v.y) << 16);
    r.y = (unsigned)bfr(v.z) | ((unsigned)bfr(v.w) << 16);
    return r;
}

// ---------------- kernel 1: row inverse norms ----------------
__global__ __launch_bounds__(256) void norm_kernel(const float* __restrict__ src,
                                                   const float* __restrict__ tgt,
                                                   float* __restrict__ inv_ns,
                                                   float* __restrict__ inv_nt) {
    int wave = (blockIdx.x * blockDim.x + threadIdx.x) >> 6;
    int lane = threadIdx.x & 63;
    const float* row;
    float* out;
    if (wave < BB * NN) { row = src + (size_t)wave * DD; out = inv_ns + wave; }
    else                { row = tgt + (size_t)(wave - BB * NN) * DD; out = inv_nt + (wave - BB * NN); }
    float2 v = ((const float2*)row)[lane];
    float s = v.x * v.x + v.y * v.y;
    #pragma unroll
    for (int off = 32; off; off >>= 1) s += __shfl_xor(s, off, 64);
    if (lane == 0) *out = 1.0f / fmaxf(sqrtf(s), 1e-12f);
}

// ---------------- kernel 2: MFMA bf16 cost GEMM -> W = exp(-C/eps) ----------------
#define RS 136

__global__ __launch_bounds__(256) void cost_mfma_kernel(const float* __restrict__ S,
                                                        const float* __restrict__ T,
                                                        const float* __restrict__ inv_ns,
                                                        const float* __restrict__ inv_nt,
                                                        unsigned short* __restrict__ W) {
    __shared__ unsigned short sA[128 * RS];
    __shared__ unsigned short sB[128 * RS];
    int bid = blockIdx.x;
    int b  = bid >> 4;
    int i0 = ((bid >> 2) & 3) * 128;
    int j0 = (bid & 3) * 128;
    int t  = threadIdx.x;

    {
        int r = t >> 1, h = t & 1;
        int gra = b * NN + i0 + r;
        int grb = b * MM + j0 + r;
        float sca = inv_ns[gra], scb = inv_nt[grb];
        const float4* pS = (const float4*)(S + (size_t)gra * DD + h * 64);
        const float4* pT = (const float4*)(T + (size_t)grb * DD + h * 64);
        unsigned short* dA = &sA[r * RS + h * 64];
        unsigned short* dB = &sB[r * RS + h * 64];
        #pragma unroll
        for (int c4 = 0; c4 < 16; ++c4) {
            float4 v = pS[c4];
            v.x *= sca; v.y *= sca; v.z *= sca; v.w *= sca;
            *(uint2*)&dA[c4 * 4] = pk4(v);
            float4 u = pT[c4];
            u.x *= scb; u.y *= scb; u.z *= scb; u.w *= scb;
            *(uint2*)&dB[c4 * 4] = pk4(u);
        }
    }
    __syncthreads();

    int l = t & 63, w = t >> 6;
    int wr = (w >> 1) * 64, wc = (w & 1) * 64;
    int fr = l & 15, fo = (l >> 4) * 8;

    f32x4 acc[4][4];
    #pragma unroll
    for (int m = 0; m < 4; ++m)
        #pragma unroll
        for (int n = 0; n < 4; ++n)
            acc[m][n] = (f32x4){0.f, 0.f, 0.f, 0.f};

    #pragma unroll
    for (int kk = 0; kk < 4; ++kk) {
        bf16x8 af[4], bfv[4];
        #pragma unroll
        for (int m = 0; m < 4; ++m)
            af[m] = *(bf16x8*)&sA[(wr + m * 16 + fr) * RS + kk * 32 + fo];
        #pragma unroll
        for (int n = 0; n < 4; ++n)
            bfv[n] = *(bf16x8*)&sB[(wc + n * 16 + fr) * RS + kk * 32 + fo];
        #pragma unroll
        for (int m = 0; m < 4; ++m)
            #pragma unroll
            for (int n = 0; n < 4; ++n)
                acc[m][n] = __builtin_amdgcn_mfma_f32_16x16x32_bf16(af[m], bfv[n], acc[m][n], 0, 0, 0);
    }

    int rb = (l >> 4) * 4;
    #pragma unroll
    for (int m = 0; m < 4; ++m) {
        #pragma unroll
        for (int n = 0; n < 4; ++n) {
            #pragma unroll
            for (int r = 0; r < 4; ++r) {
                int gi = b * NN + i0 + wr + m * 16 + rb + r;
                int gj = j0 + wc + n * 16 + fr;
                float c = acc[m][n][r];
                float cost = fmaxf(2.0f - 2.0f * c, 0.0f);
                W[(size_t)gi * MM + gj] = bfr(__expf(-20.0f * cost));
            }
        }
    }
}

// ---------------- kernel 3: register-resident Sinkhorn, 8 blocks/batch ----------------
// Block (b,q) owns W[b][:, 64q..64q+64) in VGPRs (32/thread): thread (rg=t>>3,
// c8=t&7) holds row-pairs {2(rg+64pp), +1} x cols [8c8, 8c8+8).  512 blocks ->
// 2 blocks/CU so one block's barrier spin overlaps the other's compute.
__global__ __launch_bounds__(512, 4) void sinkhorn_kernel(const unsigned short* __restrict__ W,
                                                          float* __restrict__ Sp,
                                                          unsigned int* __restrict__ bar,
                                                          float* __restrict__ dist4) {
    int gid = blockIdx.x;
    int b = gid & 63, q = gid >> 6;          // q 0..7
    const unsigned short* slab = W + (size_t)b * NN * MM + q * 64;

    __shared__ float    eu_s[NN];
    __shared__ unsigned eu_pk[NN / 2];
    __shared__ float    ev_f[64];
    __shared__ unsigned ev_pk[32];
    __shared__ float    part[8 * 68];
    __shared__ float    red[8];

    int t = threadIdx.x;
    int w = t >> 6, lane = t & 63;
    int rg = t >> 3, c8 = t & 7;

    // ---- one-time load: whole slab into registers ----
    uint4 pa[4], pb[4];
    #pragma unroll
    for (int pp = 0; pp < 4; ++pp) {
        const unsigned short* r0 = slab + (size_t)(2 * (rg + 64 * pp)) * MM + c8 * 8;
        pa[pp] = *(const uint4*)r0;
        pb[pp] = *(const uint4*)(r0 + MM);
    }

    if (t < 32) ev_pk[t] = 0x3F803F80u;
    if (t < 64) ev_f[t] = 1.0f;
    __syncthreads();

    unsigned int* ctr = bar + b * 16;

    for (int it = 0; it < ITERS; ++it) {
        float* spb = Sp + (size_t)(it & 1) * (BB * 8 * NN);

        // ---- phase A: row sums over own 64 cols from registers ----
        uint4 evv = *(uint4*)&ev_pk[c8 * 4];
        #pragma unroll
        for (int pp = 0; pp < 4; ++pp) {
            float ra = 0.0f, rb2 = 0.0f;
            ra  = fdot2bf(pa[pp].x, evv.x, ra);
            ra  = fdot2bf(pa[pp].y, evv.y, ra);
            ra  = fdot2bf(pa[pp].z, evv.z, ra);
            ra  = fdot2bf(pa[pp].w, evv.w, ra);
            rb2 = fdot2bf(pb[pp].x, evv.x, rb2);
            rb2 = fdot2bf(pb[pp].y, evv.y, rb2);
            rb2 = fdot2bf(pb[pp].z, evv.z, rb2);
            rb2 = fdot2bf(pb[pp].w, evv.w, rb2);
            ra  += __shfl_xor(ra, 1, 64);  ra  += __shfl_xor(ra, 2, 64);
            ra  += __shfl_xor(ra, 4, 64);
            rb2 += __shfl_xor(rb2, 1, 64); rb2 += __shfl_xor(rb2, 2, 64);
            rb2 += __shfl_xor(rb2, 4, 64);
            if (c8 == 0) {
                int p = rg + 64 * pp;
                float2 v = make_float2(ra, rb2);
                __hip_atomic_store((unsigned long long*)&spb[((size_t)b * 8 + q) * NN + 2 * p],
                                   *(unsigned long long*)&v,
                                   __ATOMIC_RELAXED, __HIP_MEMORY_SCOPE_AGENT);
            }
        }
        __syncthreads();   // drains vmcnt(0): partials visible before arrival add

        if (t == 0) {
            __hip_atomic_fetch_add(ctr, 1u, __ATOMIC_RELAXED, __HIP_MEMORY_SCOPE_AGENT);
            unsigned tgt = 8u * (unsigned)(it + 1);
            while (__hip_atomic_load(ctr, __ATOMIC_RELAXED, __HIP_MEMORY_SCOPE_AGENT) < tgt)
                __builtin_amdgcn_s_sleep(1);
        }
        __syncthreads();

        // ---- fused gather + eu + pack: rows (2t, 2t+1), 8 slabs, 8B loads ----
        if (t < 256) {
            const unsigned long long* gp =
                (const unsigned long long*)(spb + (size_t)b * 8 * NN) + t;
            unsigned long long u0 = __hip_atomic_load(gp + 0 * (NN / 2), __ATOMIC_RELAXED, __HIP_MEMORY_SCOPE_AGENT);
            unsigned long long u1 = __hip_atomic_load(gp + 1 * (NN / 2), __ATOMIC_RELAXED, __HIP_MEMORY_SCOPE_AGENT);
            unsigned long long u2 = __hip_atomic_load(gp + 2 * (NN / 2), __ATOMIC_RELAXED, __HIP_MEMORY_SCOPE_AGENT);
            unsigned long long u3 = __hip_atomic_load(gp + 3 * (NN / 2), __ATOMIC_RELAXED, __HIP_MEMORY_SCOPE_AGENT);
            unsigned long long u4 = __hip_atomic_load(gp + 4 * (NN / 2), __ATOMIC_RELAXED, __HIP_MEMORY_SCOPE_AGENT);
            unsigned long long u5 = __hip_atomic_load(gp + 5 * (NN / 2), __ATOMIC_RELAXED, __HIP_MEMORY_SCOPE_AGENT);
            unsigned long long u6 = __hip_atomic_load(gp + 6 * (NN / 2), __ATOMIC_RELAXED, __HIP_MEMORY_SCOPE_AGENT);
            unsigned long long u7 = __hip_atomic_load(gp + 7 * (NN / 2), __ATOMIC_RELAXED, __HIP_MEMORY_SCOPE_AGENT);
            float2 f0 = *(float2*)&u0, f1 = *(float2*)&u1, f2 = *(float2*)&u2, f3 = *(float2*)&u3;
            float2 f4 = *(float2*)&u4, f5 = *(float2*)&u5, f6 = *(float2*)&u6, f7 = *(float2*)&u7;
            float s0 = (f0.x + f1.x) + (f2.x + f3.x) + ((f4.x + f5.x) + (f6.x + f7.x));
            float s1 = (f0.y + f1.y) + (f2.y + f3.y) + ((f4.y + f5.y) + (f6.y + f7.y));
            float e0 = A_CONST / s0, e1 = A_CONST / s1;
            eu_s[2 * t]     = e0;
            eu_s[2 * t + 1] = e1;
            eu_pk[t] = pack2(e0, e1);
        }
        __syncthreads();

        // ---- phase B: col sums over own 64 cols from registers ----
        float a0 = 0, a1 = 0, a2 = 0, a3 = 0, a4 = 0, a5 = 0, a6 = 0, a7 = 0;
        #pragma unroll
        for (int pp = 0; pp < 4; ++pp) {
            unsigned ep = eu_pk[rg + 64 * pp];
            uint4 u = pa[pp], u2 = pb[pp];
            a0 = fdot2bf(__builtin_amdgcn_perm(u2.x, u.x, 0x05040100u), ep, a0);
            a1 = fdot2bf(__builtin_amdgcn_perm(u2.x, u.x, 0x07060302u), ep, a1);
            a2 = fdot2bf(__builtin_amdgcn_perm(u2.y, u.y, 0x05040100u), ep, a2);
            a3 = fdot2bf(__builtin_amdgcn_perm(u2.y, u.y, 0x07060302u), ep, a3);
            a4 = fdot2bf(__builtin_amdgcn_perm(u2.z, u.z, 0x05040100u), ep, a4);
            a5 = fdot2bf(__builtin_amdgcn_perm(u2.z, u.z, 0x07060302u), ep, a5);
            a6 = fdot2bf(__builtin_amdgcn_perm(u2.w, u.w, 0x05040100u), ep, a6);
            a7 = fdot2bf(__builtin_amdgcn_perm(u2.w, u.w, 0x07060302u), ep, a7);
        }
        a0 += __shfl_xor(a0, 8, 64); a0 += __shfl_xor(a0, 16, 64); a0 += __shfl_xor(a0, 32, 64);
        a1 += __shfl_xor(a1, 8, 64); a1 += __shfl_xor(a1, 16, 64); a1 += __shfl_xor(a1, 32, 64);
        a2 += __shfl_xor(a2, 8, 64); a2 += __shfl_xor(a2, 16, 64); a2 += __shfl_xor(a2, 32, 64);
        a3 += __shfl_xor(a3, 8, 64); a3 += __shfl_xor(a3, 16, 64); a3 += __shfl_xor(a3, 32, 64);
        a4 += __shfl_xor(a4, 8, 64); a4 += __shfl_xor(a4, 16, 64); a4 += __shfl_xor(a4, 32, 64);
        a5 += __shfl_xor(a5, 8, 64); a5 += __shfl_xor(a5, 16, 64); a5 += __shfl_xor(a5, 32, 64);
        a6 += __shfl_xor(a6, 8, 64); a6 += __shfl_xor(a6, 16, 64); a6 += __shfl_xor(a6, 32, 64);
        a7 += __shfl_xor(a7, 8, 64); a7 += __shfl_xor(a7, 16, 64); a7 += __shfl_xor(a7, 32, 64);
        if (lane < 8) {
            *(float4*)&part[w * 68 + lane * 8]     = make_float4(a0, a1, a2, a3);
            *(float4*)&part[w * 68 + lane * 8 + 4] = make_float4(a4, a5, a6, a7);
        }
        __syncthreads();

        // ---- fused ev + pack: col pairs (2t, 2t+1) ----
        if (t < 32) {
            float s0 = 0.0f, s1 = 0.0f;
            #pragma unroll
            for (int ww = 0; ww < 8; ++ww) {
                s0 += part[ww * 68 + 2 * t];
                s1 += part[ww * 68 + 2 * t + 1];
            }
            float e0 = B_CONST / s0, e1 = B_CONST / s1;
            ev_f[2 * t]     = e0;
            ev_f[2 * t + 1] = e1;
            ev_pk[t] = pack2(e0, e1);
        }
        __syncthreads();
    }

    // ---- fused distance partial from resident registers ----
    float evr[8];
    #pragma unroll
    for (int k = 0; k < 8; ++k) evr[k] = ev_f[c8 * 8 + k];
    float dacc = 0.0f;
    #pragma unroll
    for (int pp = 0; pp < 4; ++pp) {
        int p = rg + 64 * pp;
        float euA = eu_s[2 * p], euB = eu_s[2 * p + 1];
        uint4 u = pa[pp], u2 = pb[pp];
        {
            float w0 = bflo(u.x), w1 = bfhi(u.x), w2 = bflo(u.y), w3 = bfhi(u.y);
            float w4 = bflo(u.z), w5 = bfhi(u.z), w6 = bflo(u.w), w7 = bfhi(u.w);
            float s = w0 * __logf(w0) * evr[0] + w1 * __logf(w1) * evr[1]
                    + w2 * __logf(w2) * evr[2] + w3 * __logf(w3) * evr[3]
                    + w4 * __logf(w4) * evr[4] + w5 * __logf(w5) * evr[5]
                    + w6 * __logf(w6) * evr[6] + w7 * __logf(w7) * evr[7];
            dacc += euA * s;
        }
        {
            float w0 = bflo(u2.x), w1 = bfhi(u2.x), w2 = bflo(u2.y), w3 = bfhi(u2.y);
            float w4 = bflo(u2.z), w5 = bfhi(u2.z), w6 = bflo(u2.w), w7 = bfhi(u2.w);
            float s = w0 * __logf(w0) * evr[0] + w1 * __logf(w1) * evr[1]
                    + w2 * __logf(w2) * evr[2] + w3 * __logf(w3) * evr[3]
                    + w4 * __logf(w4) * evr[4] + w5 * __logf(w5) * evr[5]
                    + w6 * __logf(w6) * evr[6] + w7 * __logf(w7) * evr[7];
            dacc += euB * s;
        }
    }
    #pragma unroll
    for (int off = 32; off; off >>= 1) dacc += __shfl_xor(dacc, off, 64);
    if (lane == 0) red[w] = dacc;
    __syncthreads();
    if (t == 0) {
        float s = 0.0f;
        #pragma unroll
        for (int i = 0; i < 8; ++i) s += red[i];
        dist4[gid] = s;
    }
}

// ---------------- kernel 4: mean over 512 partials ----------------
__global__ __launch_bounds__(512) void mean_kernel(const float* __restrict__ dist4,
                                                   float* __restrict__ out) {
    __shared__ float red[8];
    int t = threadIdx.x;
    float v = dist4[t];
    #pragma unroll
    for (int off = 32; off; off >>= 1) v += __shfl_xor(v, off, 64);
    if ((t & 63) == 0) red[t >> 6] = v;
    __syncthreads();
    if (t == 0) {
        float s = 0.0f;
        #pragma unroll
        for (int i = 0; i < 8; ++i) s += red[i];
        out[0] = -SINK_EPS_F * s * (1.0f / 64.0f);
    }
}

extern "C" void kernel_launch(void* const* d_in, const int* in_sizes, int n_in,
                              void* d_out, int out_size, void* d_ws, size_t ws_size,
                              hipStream_t stream) {
    const float* src = (const float*)d_in[0];
    const float* tgt = (const float*)d_in[1];
    char* ws = (char*)d_ws;

    float*          inv_ns = (float*)(ws);
    float*          inv_nt = (float*)(ws + 131072);
    unsigned short* W      = (unsigned short*)(ws + 262144);
    float*          Sp     = (float*)(ws + 262144 + 33554432);                 // 2 MB (2 bufs x 64 x 8 x 512)
    float*          dist4  = (float*)(ws + 262144 + 33554432 + 2097152);
    unsigned int*   bar    = (unsigned int*)(ws + 262144 + 33554432 + 2097152 + 4096);
    float*          out    = (float*)d_out;

    hipMemsetAsync(bar, 0, 64 * 16 * sizeof(unsigned int), stream);

    hipLaunchKernelGGL(norm_kernel,      dim3(16384), dim3(256), 0, stream, src, tgt, inv_ns, inv_nt);
    hipLaunchKernelGGL(cost_mfma_kernel, dim3(1024),  dim3(256), 0, stream, src, tgt, inv_ns, inv_nt, W);
    hipLaunchKernelGGL(sinkhorn_kernel,  dim3(512),   dim3(512), 0, stream, W, Sp, bar, dist4);
    hipLaunchKernelGGL(mean_kernel,      dim3(1),     dim3(512), 0, stream, dist4, out);
}